// Round 1
// 379.088 us; speedup vs baseline: 1.0868x; 1.0868x over previous
//
#include <hip/hip_runtime.h>
#include <hip/hip_bf16.h>
#include <stdint.h>

// Problem constants (reference: B,TQ,TK,D,DV = 8,2048,2048,1024,1024)
#define B_  8
#define TQ_ 2048
#define TK_ 2048
#define D_  1024
#define DV_ 1024

typedef __attribute__((ext_vector_type(8))) short  short8;
typedef __attribute__((ext_vector_type(4))) float  floatx4;

__device__ __forceinline__ void async_copy16(const void* g, void* l) {
  // 16B-per-lane global->LDS DMA. LDS dest is wave-uniform base + lane*16.
  __builtin_amdgcn_global_load_lds(
      (const __attribute__((address_space(1))) unsigned int*)g,
      (__attribute__((address_space(3))) unsigned int*)l,
      16, 0, 0);
}

__device__ __forceinline__ ushort f2bf(float f) {
  union { __hip_bfloat16 b; ushort u; } cv;
  cv.b = __float2bfloat16(f);
  return cv.u;
}

__device__ __forceinline__ float bf2f(ushort u) {
  union { ushort u; __hip_bfloat16 b; } cv;
  cv.u = u;
  return __bfloat162float(cv.b);
}

// ---------------- fused prep kernel (unchanged, verified) ----------------
// grid (32,16,24), block 256.
//   z  0..7 : q fp32 -> bf16 (same layout), batch z
//   z  8..15: k [D][TK] -> ktb [TK][D], batch z-8   (64x64 tiled transpose)
//   z 16..23: v [TK][DV] -> vtb [DV][TK], batch z-16

__device__ __forceinline__ void transpose_body(const float* __restrict__ in,
                                               ushort* __restrict__ out,
                                               int R, int C, int r0, int c0,
                                               float (*tile)[65]) {
  const int t = threadIdx.x;
  {
    const int row = t >> 4, col = (t & 15) * 4;
    #pragma unroll
    for (int ro = 0; ro < 4; ro++) {
      const float4 f = *(const float4*)&in[(size_t)(r0 + ro * 16 + row) * C + c0 + col];
      tile[ro * 16 + row][col + 0] = f.x;
      tile[ro * 16 + row][col + 1] = f.y;
      tile[ro * 16 + row][col + 2] = f.z;
      tile[ro * 16 + row][col + 3] = f.w;
    }
  }
  __syncthreads();
  {
    const int c = t >> 4, rg = (t & 15) * 4;
    #pragma unroll
    for (int ro = 0; ro < 4; ro++) {
      const int cc = ro * 16 + c;
      ushort4 o;
      o.x = f2bf(tile[rg + 0][cc]);
      o.y = f2bf(tile[rg + 1][cc]);
      o.z = f2bf(tile[rg + 2][cc]);
      o.w = f2bf(tile[rg + 3][cc]);
      *(ushort4*)&out[(size_t)(c0 + cc) * R + r0 + rg] = o;
    }
  }
}

__global__ void prep(const float* __restrict__ q, const float* __restrict__ k,
                     const float* __restrict__ v, ushort* __restrict__ qb,
                     ushort* __restrict__ ktb, ushort* __restrict__ vtb) {
  __shared__ float tile[64][65];
  const int task = blockIdx.z >> 3;
  const int z    = blockIdx.z & 7;
  if (task == 0) {
    const float4* in  = (const float4*)(q + (size_t)z * TQ_ * D_);
    ushort4*      oup = (ushort4*)(qb + (size_t)z * TQ_ * D_);
    const int i0 = (blockIdx.y * 32 + blockIdx.x) * 1024 + threadIdx.x;
    #pragma unroll
    for (int it = 0; it < 4; it++) {
      const int i = i0 + it * 256;
      float4 f = in[i];
      ushort4 o;
      o.x = f2bf(f.x); o.y = f2bf(f.y); o.z = f2bf(f.z); o.w = f2bf(f.w);
      oup[i] = o;
    }
  } else if (task == 1) {
    transpose_body(k + (size_t)z * D_ * TK_, ktb + (size_t)z * TK_ * D_,
                   D_, TK_, blockIdx.y * 64, blockIdx.x * 64, tile);
  } else {
    transpose_body(v + (size_t)z * TK_ * DV_, vtb + (size_t)z * DV_ * TK_,
                   TK_, DV_, blockIdx.x * 64, blockIdx.y * 64, tile);
  }
}

// ---------------- 256x256-tile 8-phase GEMM core ----------------
// BM=BN=256, BK=64, 512 threads = 8 waves (2 wm x 4 wn), per-wave C = 128x64
// = acc[8][4] fragments of mfma_f32_16x16x32_bf16.
// LDS 128 KiB: A(p) @ p*32768 (256 rows x 128B), B(p) @ 65536 + p*32768.
// Swizzle: within a row (8 chunks of 16B), slot s holds global chunk
// s ^ (row&7); applied on the per-lane GLOBAL address at stage time (LDS dest
// linear, as global_load_lds requires), and on the ds_read address at use.
// Schedule per K-tile tt (4 phases, quadrants (mh,nh)):
//  P1: read A(mh0)[8] + B(nh0)[4]; stage B(tt+1) both halves | bar | 16 MFMA | bar
//  P2: read B(nh1)[4]                                        | bar | 16 MFMA | bar
//  P3: read A(mh1)[8]                                        | bar | 16 MFMA | bar
//  P4: read B(nh0)[4]; stage A(tt+2) both halves; vmcnt(4)   | bar | 16 MFMA | bar
// Retirement proof: A(tt) last read P3 -> A region overwritten P4 (barrier-
// separated); B(tt) last read P4 -> B region overwritten at P(tt+1)1.
// vmcnt(4) leaves exactly the just-issued A(tt+2) pair in flight; everything
// tile tt+1 needs is drained before its first read. Never vmcnt(0) mid-loop.

#define WG_BARRIER() do { asm volatile("" ::: "memory");        \
                          __builtin_amdgcn_s_barrier();         \
                          asm volatile("" ::: "memory"); } while (0)
#define VMCNT(n) asm volatile("s_waitcnt vmcnt(" #n ")" ::: "memory")

// stage one 128-row x 64-col bf16 panel (16 KB) = 2 DMA issues x 512 lanes x 16B
__device__ __forceinline__ void stage128(const ushort* __restrict__ gp, int grow0,
                                         int k0, int KD, char* lds, int t) {
  const int rr  = t >> 3;           // row within 64-row issue group
  const int s   = t & 7;            // 16B slot within row
  const int gch = s ^ (rr & 7);     // pre-swizzled global chunk
  const char* g0 = (const char*)(gp + (size_t)(grow0 + rr) * KD + k0) + gch * 16;
  async_copy16(g0, lds + t * 16);
  const char* g1 = (const char*)(gp + (size_t)(grow0 + 64 + rr) * KD + k0) + gch * 16;
  async_copy16(g1, lds + 8192 + t * 16);
}

template <int MH>
__device__ __forceinline__ void loadA(short8 (&a)[4][2], const char* Ab,
                                      int rowA, int off0, int off1) {
  #pragma unroll
  for (int j = 0; j < 4; ++j) {
    const char* p = Ab + rowA + (MH * 4 + j) * 2048;   // 16 rows * 128B
    a[j][0] = *(const short8*)(p + off0);
    a[j][1] = *(const short8*)(p + off1);
  }
}

template <int NH>
__device__ __forceinline__ void loadB(short8 (&b)[2][2], const char* Bb,
                                      int rowB, int off0, int off1) {
  #pragma unroll
  for (int i = 0; i < 2; ++i) {
    const char* p = Bb + rowB + (NH * 2 + i) * 2048;
    b[i][0] = *(const short8*)(p + off0);
    b[i][1] = *(const short8*)(p + off1);
  }
}

template <int MH, int NH>
__device__ __forceinline__ void qmfma(floatx4 (&acc)[8][4], const short8 (&a)[4][2],
                                      const short8 (&b)[2][2]) {
  #pragma unroll
  for (int j = 0; j < 4; ++j)
    #pragma unroll
    for (int i = 0; i < 2; ++i) {
      floatx4 c = acc[MH * 4 + j][NH * 2 + i];
      c = __builtin_amdgcn_mfma_f32_16x16x32_bf16(a[j][0], b[i][0], c, 0, 0, 0);
      c = __builtin_amdgcn_mfma_f32_16x16x32_bf16(a[j][1], b[i][1], c, 0, 0, 0);
      acc[MH * 4 + j][NH * 2 + i] = c;
    }
}

template <int KDIM>
__device__ __forceinline__ void gemm_core8(const ushort* __restrict__ Ap,
                                           const ushort* __restrict__ Bp,
                                           char* lds, int bm0, int bn0,
                                           floatx4 (&acc)[8][4]) {
  const int t    = threadIdx.x;
  const int lane = t & 63;
  const int w    = t >> 6;
  const int wm   = w >> 2, wn = w & 3;
  const int lc   = lane & 15, q = lane >> 4;
  const int sw   = lc & 7;                 // (row & 7) for all this lane's rows
  const int off0 = ((q)     ^ sw) * 16;    // ks=0 chunk slot
  const int off1 = ((4 + q) ^ sw) * 16;    // ks=1 chunk slot
  const int rowA = (wm * 128 + lc) * 128;
  const int rowB = (wn * 64  + lc) * 128;
  constexpr int NT = KDIM / 64;

  #pragma unroll
  for (int mi = 0; mi < 8; ++mi)
    #pragma unroll
    for (int ni = 0; ni < 4; ++ni)
      acc[mi][ni] = (floatx4){0.f, 0.f, 0.f, 0.f};

  char* A0b = lds;
  char* A1b = lds + 32768;
  char* B0b = lds + 65536;

  // prologue: A(0), B(0), A(1); drain to 4 (A(1) pair allowed in flight)
  stage128(Ap, bm0,       0,  KDIM, A0b,         t);
  stage128(Ap, bm0 + 128, 0,  KDIM, A0b + 16384, t);
  stage128(Bp, bn0,       0,  KDIM, B0b,         t);
  stage128(Bp, bn0 + 128, 0,  KDIM, B0b + 16384, t);
  stage128(Ap, bm0,       64, KDIM, A1b,         t);
  stage128(Ap, bm0 + 128, 64, KDIM, A1b + 16384, t);
  VMCNT(4);
  WG_BARRIER();

  short8 a[4][2], b[2][2];
  #pragma unroll 2
  for (int tt = 0; tt < NT; ++tt) {
    char* Ab = lds + (tt & 1) * 32768;
    char* Bb = lds + 65536 + (tt & 1) * 32768;
    char* Bn = lds + 65536 + ((tt + 1) & 1) * 32768;

    // ---- Phase 1: quadrant (0,0); stage B(tt+1) ----
    loadA<0>(a, Ab, rowA, off0, off1);
    loadB<0>(b, Bb, rowB, off0, off1);
    if (tt + 1 < NT) {
      const int kb = (tt + 1) * 64;
      stage128(Bp, bn0,       kb, KDIM, Bn,         t);
      stage128(Bp, bn0 + 128, kb, KDIM, Bn + 16384, t);
    }
    WG_BARRIER();
    __builtin_amdgcn_s_setprio(1);
    qmfma<0, 0>(acc, a, b);
    __builtin_amdgcn_s_setprio(0);
    WG_BARRIER();

    // ---- Phase 2: quadrant (0,1) ----
    loadB<1>(b, Bb, rowB, off0, off1);
    WG_BARRIER();
    __builtin_amdgcn_s_setprio(1);
    qmfma<0, 1>(acc, a, b);
    __builtin_amdgcn_s_setprio(0);
    WG_BARRIER();

    // ---- Phase 3: quadrant (1,1) ----
    loadA<1>(a, Ab, rowA, off0, off1);
    WG_BARRIER();
    __builtin_amdgcn_s_setprio(1);
    qmfma<1, 1>(acc, a, b);
    __builtin_amdgcn_s_setprio(0);
    WG_BARRIER();

    // ---- Phase 4: quadrant (1,0); stage A(tt+2); counted vmcnt ----
    loadB<0>(b, Bb, rowB, off0, off1);
    if (tt + 2 < NT) {
      const int ka = (tt + 2) * 64;
      stage128(Ap, bm0,       ka, KDIM, Ab,         t);
      stage128(Ap, bm0 + 128, ka, KDIM, Ab + 16384, t);
      VMCNT(4);
    } else {
      VMCNT(0);   // tail drain only
    }
    WG_BARRIER();
    __builtin_amdgcn_s_setprio(1);
    qmfma<1, 0>(acc, a, b);
    __builtin_amdgcn_s_setprio(0);
    WG_BARRIER();
  }
}

// GEMM1: P = exp(tanh(Q K + b)) in bf16; row sums of the bf16-rounded P via
// per-16-lane shuffle reduce + one atomicAdd per row-fragment.
__global__ __launch_bounds__(512, 2)
void gemm_qk(const ushort* __restrict__ Q, const ushort* __restrict__ Kt,
             const float* __restrict__ bias, ushort* __restrict__ P,
             float* __restrict__ lsum) {
  __shared__ short8 ldsv[8192];       // 128 KiB
  char* lds = (char*)ldsv;
  const int z   = blockIdx.z;
  const int bm0 = blockIdx.y * 256;
  const int bn0 = blockIdx.x * 256;

  floatx4 acc[8][4];
  gemm_core8<D_>(Q + (size_t)z * TQ_ * D_, Kt + (size_t)z * TK_ * D_,
                 lds, bm0, bn0, acc);

  const int lane = threadIdx.x & 63;
  const int w    = threadIdx.x >> 6;
  const int wm   = w >> 2, wn = w & 3;
  const int lc   = lane & 15, q = lane >> 4;
  ushort* Pb = P + (size_t)z * TQ_ * TK_;
  float*  lz = lsum + z * TQ_;

  #pragma unroll
  for (int mi = 0; mi < 8; ++mi) {
    const int grow = bm0 + wm * 128 + mi * 16 + (q << 2);
    float rs[4] = {0.f, 0.f, 0.f, 0.f};
    #pragma unroll
    for (int ni = 0; ni < 4; ++ni) {
      const int gcol = bn0 + wn * 64 + ni * 16 + lc;
      const float bj = bias[gcol];
      #pragma unroll
      for (int r = 0; r < 4; ++r) {
        float s = acc[mi][ni][r] + bj;
        // tanh(s) = 1 - 2/(e^{2s}+1); safe at +/-inf. exp(tanh) in [0.37,2.72]
        // => softmax needs no max subtraction.
        float tnh = 1.f - 2.f / (__expf(2.f * s) + 1.f);
        float p   = __expf(tnh);
        ushort pu = f2bf(p);
        Pb[(size_t)(grow + r) * TK_ + gcol] = pu;
        rs[r] += bf2f(pu);
      }
    }
    #pragma unroll
    for (int r = 0; r < 4; ++r) {
      rs[r] += __shfl_xor(rs[r], 1, 64);
      rs[r] += __shfl_xor(rs[r], 2, 64);
      rs[r] += __shfl_xor(rs[r], 4, 64);
      rs[r] += __shfl_xor(rs[r], 8, 64);
    }
    if (lc == 0) {
      #pragma unroll
      for (int r = 0; r < 4; ++r) atomicAdd(&lz[grow + r], rs[r]);
    }
  }
}

// GEMM2: out = (P Vt^T) / lsum, fp32 out
__global__ __launch_bounds__(512, 2)
void gemm_pv(const ushort* __restrict__ P, const ushort* __restrict__ Vt,
             const float* __restrict__ lsum, float* __restrict__ out) {
  __shared__ short8 ldsv[8192];       // 128 KiB
  char* lds = (char*)ldsv;
  const int z   = blockIdx.z;
  const int bm0 = blockIdx.y * 256;
  const int bn0 = blockIdx.x * 256;

  floatx4 acc[8][4];
  gemm_core8<TK_>(P + (size_t)z * TQ_ * TK_, Vt + (size_t)z * DV_ * TK_,
                  lds, bm0, bn0, acc);

  const int lane = threadIdx.x & 63;
  const int w    = threadIdx.x >> 6;
  const int wm   = w >> 2, wn = w & 3;
  const int lc   = lane & 15, q = lane >> 4;
  float* ob = out + (size_t)z * TQ_ * DV_;
  const float* lz = lsum + z * TQ_;

  #pragma unroll
  for (int mi = 0; mi < 8; ++mi) {
    const int grow = bm0 + wm * 128 + mi * 16 + (q << 2);
    float linv[4];
    #pragma unroll
    for (int r = 0; r < 4; ++r) linv[r] = 1.f / lz[grow + r];
    #pragma unroll
    for (int ni = 0; ni < 4; ++ni) {
      const int gcol = bn0 + wn * 64 + ni * 16 + lc;
      #pragma unroll
      for (int r = 0; r < 4; ++r)
        ob[(size_t)(grow + r) * DV_ + gcol] = acc[mi][ni][r] * linv[r];
    }
  }
}

// ---------------- launch ----------------
// Workspace layout (bytes):
//   qb   @ 0         : 8*2048*1024*2 = 33554432   (Q bf16)
//   ktb  @ 33554432  : 33554432                   (K^T bf16, [TK][D])
//   vtb  @ 67108864  : 33554432                   (V^T bf16, [DV][TK])
//   P    @ 100663296 : 8*2048*2048*2 = 67108864   (exp(tanh(S)) bf16)
//   lsum @ 167772160 : 8*2048*4      = 65536      (softmax denominators)
// Total: 167837696 bytes (~160 MB)

extern "C" void kernel_launch(void* const* d_in, const int* in_sizes, int n_in,
                              void* d_out, int out_size, void* d_ws, size_t ws_size,
                              hipStream_t stream) {
  const float* q    = (const float*)d_in[0];
  const float* k    = (const float*)d_in[1];
  const float* v    = (const float*)d_in[2];
  const float* bias = (const float*)d_in[3];
  float* out = (float*)d_out;

  char* ws = (char*)d_ws;
  ushort* qb   = (ushort*)(ws);
  ushort* ktb  = (ushort*)(ws + 33554432);
  ushort* vtb  = (ushort*)(ws + 67108864);
  ushort* P    = (ushort*)(ws + 100663296);
  float*  lsum = (float*)(ws + 167772160);

  hipMemsetAsync(lsum, 0, B_ * TQ_ * sizeof(float), stream);

  prep<<<dim3(32, 16, 24), dim3(256), 0, stream>>>(q, k, v, qb, ktb, vtb);

  gemm_qk<<<dim3(TK_ / 256, TQ_ / 256, B_), dim3(512), 0, stream>>>(qb, ktb, bias, P, lsum);
  gemm_pv<<<dim3(DV_ / 256, TQ_ / 256, B_), dim3(512), 0, stream>>>(P, vtb, lsum, out);
}